// Round 12
// baseline (159.221 us; speedup 1.0000x reference)
//
#include <hip/hip_runtime.h>
#include <hip/hip_bf16.h>
#include <stdint.h>
#include <stddef.h>

constexpr int Bc = 2;
constexpr int Sc = 4096;
constexpr int Dc = 512;
constexpr int Hc = 8;
constexpr int Wc = 32;

using bf16_t = __bf16;
using f16_t  = _Float16;
typedef __attribute__((ext_vector_type(8))) __bf16 bf16x8;
typedef __attribute__((ext_vector_type(4))) __bf16 bf16x4;
typedef __attribute__((ext_vector_type(2))) __bf16 bf16x2;
typedef __attribute__((ext_vector_type(2))) _Float16 f16x2;
typedef __attribute__((ext_vector_type(4))) float f32x4;

__device__ __forceinline__ void async_copy16(const void* g, void* l) {
    __builtin_amdgcn_global_load_lds(
        (const __attribute__((address_space(1))) void*)g,
        (__attribute__((address_space(3))) void*)l,
        16, 0, 0);
}

// All input conversions in one launch (inputs fp32 — measured round 7).
__global__ void convert_all(const float* __restrict__ x,
                            const float* __restrict__ wq, const float* __restrict__ wk,
                            const float* __restrict__ wv, const float* __restrict__ wo,
                            bf16_t* __restrict__ xc, bf16_t* __restrict__ dq,
                            bf16_t* __restrict__ dk, bf16_t* __restrict__ dv,
                            bf16_t* __restrict__ dwo) {
    const int blk = blockIdx.x;
    const float* s; bf16_t* d; int base;
    if (blk < 4096) { s = x; d = xc; base = blk * 1024; }
    else {
        const int r = blk - 4096, which = r >> 8;
        s = (which == 0) ? wq : (which == 1) ? wk : (which == 2) ? wv : wo;
        d = (which == 0) ? dq : (which == 1) ? dk : (which == 2) ? dv : dwo;
        base = (r & 255) * 1024;
    }
    const int i = base + threadIdx.x * 4;
    const float4 v = *(const float4*)(s + i);
    bf16x4 o; o[0] = (bf16_t)v.x; o[1] = (bf16_t)v.y;
    o[2] = (bf16_t)v.z; o[3] = (bf16_t)v.w;
    *(bf16x4*)(d + i) = o;
}

// C = A @ B^T, BK=64 via two sequential 32-wide panels (contiguous
// global_load_lds fill preserved). 32 MFMA per barrier-pair.
// nPerB>0: virtual B=[B0;B1;B2]. OMODE: 0=bf16, 1=f32, 2=f16 out.
template<int BM, int BN, int TM, int TN, int OMODE>
__global__ __launch_bounds__(256) void gemm_bt2(
    const bf16_t* __restrict__ A, int lda,
    const bf16_t* __restrict__ B0, const bf16_t* __restrict__ B1,
    const bf16_t* __restrict__ B2, int ldb, int nPerB,
    void* __restrict__ C, int ldc, int K)
{
    __shared__ __align__(1024) bf16_t Alds[2][BM * 32];
    __shared__ __align__(1024) bf16_t Blds[2][BN * 32];

    const int tid  = threadIdx.x;
    const int lane = tid & 63;
    const int wv   = tid >> 6;
    const int wm   = wv >> 1;
    const int wn   = wv & 1;
    const int r    = lane & 15;
    const int q4   = lane >> 4;

    const int blkM = blockIdx.x * BM;
    const int colC = blockIdx.y * BN;

    const bf16_t* Bp = B0;
    int nB = colC;
    if (nPerB > 0) {
        int wsel = colC / nPerB;
        nB = colC - wsel * nPerB;
        Bp = (wsel == 0) ? B0 : (wsel == 1) ? B1 : B2;
    }

    f32x4 acc[TM][TN];
    const f32x4 fzero = {0.f, 0.f, 0.f, 0.f};
    #pragma unroll
    for (int i = 0; i < TM; ++i)
        #pragma unroll
        for (int j = 0; j < TN; ++j) acc[i][j] = fzero;

    constexpr int A_LOADS = (BM * 32 * 2) / (256 * 16);
    constexpr int B_LOADS = (BN * 32 * 2) / (256 * 16);

    for (int kk = 0; kk < K; kk += 64) {
        __syncthreads();
        #pragma unroll
        for (int p = 0; p < 2; ++p) {
            #pragma unroll
            for (int i = 0; i < A_LOADS; ++i) {
                int off  = i * 4096 + tid * 16;
                int row  = off >> 6;              // 64 B per staged row
                int colb = off & 63;
                const char* g = (const char*)A +
                    ((size_t)(blkM + row) * lda + kk + p * 32) * 2 + colb;
                async_copy16(g, (char*)Alds[p] + off);
            }
            #pragma unroll
            for (int i = 0; i < B_LOADS; ++i) {
                int off  = i * 4096 + tid * 16;
                int row  = off >> 6;
                int colb = off & 63;
                const char* g = (const char*)Bp +
                    ((size_t)(nB + row) * ldb + kk + p * 32) * 2 + colb;
                async_copy16(g, (char*)Blds[p] + off);
            }
        }
        __syncthreads();

        #pragma unroll
        for (int ks = 0; ks < 2; ++ks) {
            bf16x8 af[TM], bfr[TN];
            #pragma unroll
            for (int mt = 0; mt < TM; ++mt)
                af[mt] = *(const bf16x8*)&Alds[ks][(wm * TM * 16 + mt * 16 + r) * 32 + q4 * 8];
            #pragma unroll
            for (int nt = 0; nt < TN; ++nt)
                bfr[nt] = *(const bf16x8*)&Blds[ks][(wn * TN * 16 + nt * 16 + r) * 32 + q4 * 8];

            #pragma unroll
            for (int mt = 0; mt < TM; ++mt)
                #pragma unroll
                for (int nt = 0; nt < TN; ++nt)
                    acc[mt][nt] = __builtin_amdgcn_mfma_f32_16x16x32_bf16(
                        af[mt], bfr[nt], acc[mt][nt], 0, 0, 0);
        }
    }

    #pragma unroll
    for (int mt = 0; mt < TM; ++mt) {
        #pragma unroll
        for (int nt = 0; nt < TN; ++nt) {
            int rr0 = blkM + wm * TM * 16 + mt * 16 + q4 * 4;
            int cc  = colC + wn * TN * 16 + nt * 16 + r;
            #pragma unroll
            for (int i = 0; i < 4; ++i) {
                size_t o = (size_t)(rr0 + i) * ldc + cc;
                if constexpr (OMODE == 1)      ((float*)C)[o]  = acc[mt][nt][i];
                else if constexpr (OMODE == 2) ((f16_t*)C)[o]  = (f16_t)acc[mt][nt][i];
                else                           ((bf16_t*)C)[o] = (bf16_t)acc[mt][nt][i];
            }
        }
    }
}

// Neighbor attention: one wave per (b, h, s-PAIR).  QKV rows [Q|K|V] f16.
// Phase 1: lane (sw = lane>>5 -> s = 2*sp+sw, w = lane&31 -> neighbor):
//   full 64-dim q.k via 16x uint4 loads + 32 fdot2. One softmax shuffle
//   chain serves both s-halves (xor masks < 32). No max-subtraction
//   (|score| ~ N(0,1); exp overflow needs |p|>88 — impossible).
// Phase 3: lane (sw, d2 = lane&31): all 32 neighbors of s_sw at dim pair
//   {2*d2, 2*d2+1}; dword V loads; direct bf16x2 store (no merge shuffles).
__global__ __launch_bounds__(256) void attn_pair(
    const f16_t* __restrict__ QKV,
    const int*   __restrict__ nidx,
    bf16_t*      __restrict__ attn_out)
{
    __shared__ __align__(16) float wa_lds[4][128];  // per-wave: 64 x (off, a)
    const int lane = threadIdx.x & 63;
    const int wv   = threadIdx.x >> 6;

    // XCD swizzle: contiguous sp-range per XCD for gather L2 locality.
    const int bi  = blockIdx.x;                    // 0..8191
    const int blk = (bi & 7) * 1024 + (bi >> 3);
    const int wg  = blk * 4 + wv;                  // 0..32767
    const int sp = wg & 2047;
    const int h  = (wg >> 11) & 7;
    const int b  = wg >> 14;

    const int sw = lane >> 5;
    const int w  = lane & 31;
    const int s  = 2 * sp + sw;
    const int t  = nidx[s * Wc + w];

    const char* qkvB = (const char*)QKV;
    const char* Qp = qkvB + ((size_t)b * Sc + s) * 3072 + h * 128;
    const char* Kp = qkvB + ((size_t)b * Sc + t) * 3072 + 1024 + h * 128;

    uint4 qv[8], kv[8];
    #pragma unroll
    for (int i = 0; i < 8; ++i) {
        qv[i] = *(const uint4*)(Qp + 16 * i);
        kv[i] = *(const uint4*)(Kp + 16 * i);
    }
    float p0 = 0.f, p1 = 0.f;
    #pragma unroll
    for (int i = 0; i < 8; ++i) {
        p0 = __builtin_amdgcn_fdot2(__builtin_bit_cast(f16x2, qv[i].x),
                                    __builtin_bit_cast(f16x2, kv[i].x), p0, false);
        p1 = __builtin_amdgcn_fdot2(__builtin_bit_cast(f16x2, qv[i].y),
                                    __builtin_bit_cast(f16x2, kv[i].y), p1, false);
        p0 = __builtin_amdgcn_fdot2(__builtin_bit_cast(f16x2, qv[i].z),
                                    __builtin_bit_cast(f16x2, kv[i].z), p0, false);
        p1 = __builtin_amdgcn_fdot2(__builtin_bit_cast(f16x2, qv[i].w),
                                    __builtin_bit_cast(f16x2, kv[i].w), p1, false);
    }
    const float e = __expf((p0 + p1) * 0.125f);    // 1/sqrt(64); no max-sub
    float sum = e;
    #pragma unroll
    for (int m = 1; m <= 16; m <<= 1) sum += __shfl_xor(sum, m);
    const float a = e / sum;

    {
        float2 wr; wr.x = __int_as_float(t * 3072); wr.y = a;
        *(float2*)&wa_lds[wv][2 * lane] = wr;
    }
    __syncthreads();

    // Phase 3.
    const int d2 = lane & 31;
    const float* ch = &wa_lds[wv][sw * 64];
    const char* Vp = qkvB + (size_t)b * Sc * 3072 + 2048 + h * 128 + d2 * 4;

    float acc0 = 0.f, acc1 = 0.f;
    #pragma unroll
    for (int j = 0; j < 16; ++j) {
        const float4 c = *(const float4*)(ch + 4 * j);
        {
            const unsigned v = *(const unsigned*)(Vp + __float_as_int(c.x));
            const f16x2 v2 = __builtin_bit_cast(f16x2, v);
            acc0 = fmaf(c.y, (float)v2[0], acc0);
            acc1 = fmaf(c.y, (float)v2[1], acc1);
        }
        {
            const unsigned v = *(const unsigned*)(Vp + __float_as_int(c.z));
            const f16x2 v2 = __builtin_bit_cast(f16x2, v);
            acc0 = fmaf(c.w, (float)v2[0], acc0);
            acc1 = fmaf(c.w, (float)v2[1], acc1);
        }
    }
    bf16x2 pr; pr[0] = (bf16_t)acc0; pr[1] = (bf16_t)acc1;
    *(bf16x2*)((char*)attn_out + ((size_t)b * Sc + s) * 1024 + h * 128 + d2 * 4) = pr;
}

extern "C" void kernel_launch(void* const* d_in, const int* in_sizes, int n_in,
                              void* d_out, int out_size, void* d_ws, size_t ws_size,
                              hipStream_t stream) {
    (void)in_sizes; (void)n_in; (void)out_size; (void)ws_size;
    const int* nidx = (const int*)d_in[5];
    const int M = Bc * Sc;                        // 8192
    float* out = (float*)d_out;                   // fp32 output (round-7 finding)

    char* w = (char*)d_ws;
    bf16_t* xc   = (bf16_t*)(w + 256);            // 8 MB
    bf16_t* Wqc  = xc  + 4194304;                 // 0.5 MB each
    bf16_t* Wkc  = Wqc + 262144;
    bf16_t* Wvc  = Wkc + 262144;
    bf16_t* Woc  = Wvc + 262144;
    f16_t*  qkv  = (f16_t*)(Woc + 262144);        // 24 MB, f16
    bf16_t* attnS = xc;                           // reuse x-buffer after GEMM1

    convert_all<<<5120, 256, 0, stream>>>(
        (const float*)d_in[0], (const float*)d_in[1], (const float*)d_in[2],
        (const float*)d_in[3], (const float*)d_in[4],
        xc, Wqc, Wkc, Wvc, Woc);

    // Fused QKV projection: M=8192, N=1536, K=512 (f16 out for fdot2).
    gemm_bt2<128, 128, 4, 4, 2><<<dim3(M / 128, 1536 / 128), 256, 0, stream>>>(
        xc, Dc, Wqc, Wkc, Wvc, Dc, 512, qkv, 1536, Dc);

    // Neighbor attention: one wave per (b,h,s-pair).
    attn_pair<<<(Bc * Hc * Sc) / 8, 256, 0, stream>>>(qkv, nidx, attnS);

    // Output projection: M=8192, N=512, K=512 -> fp32 d_out.
    gemm_bt2<128, 64, 4, 2, 1><<<dim3(M / 128, 512 / 64), 256, 0, stream>>>(
        attnS, 512, Woc, Woc, Woc, 512, 0, out, Dc, Dc);
}

// Round 13
// 150.063 us; speedup vs baseline: 1.0610x; 1.0610x over previous
//
#include <hip/hip_runtime.h>
#include <hip/hip_bf16.h>
#include <stdint.h>
#include <stddef.h>

constexpr int Bc = 2;
constexpr int Sc = 4096;
constexpr int Dc = 512;
constexpr int Hc = 8;
constexpr int Wc = 32;

using f16_t = _Float16;
typedef __attribute__((ext_vector_type(8))) _Float16 f16x8;
typedef __attribute__((ext_vector_type(4))) _Float16 f16x4;
typedef __attribute__((ext_vector_type(2))) _Float16 f16x2;
typedef __attribute__((ext_vector_type(4))) float f32x4;

__device__ __forceinline__ void async_copy16(const void* g, void* l) {
    __builtin_amdgcn_global_load_lds(
        (const __attribute__((address_space(1))) void*)g,
        (__attribute__((address_space(3))) void*)l,
        16, 0, 0);
}

// All input conversions in one launch (inputs fp32 — measured round 7).
// Blocks 0..4095: x (4 elem/thread). Blocks 4096..5119: the 4 weights.
__global__ void convert_all(const float* __restrict__ x,
                            const float* __restrict__ wq, const float* __restrict__ wk,
                            const float* __restrict__ wv, const float* __restrict__ wo,
                            f16_t* __restrict__ xc, f16_t* __restrict__ dq,
                            f16_t* __restrict__ dk, f16_t* __restrict__ dv,
                            f16_t* __restrict__ dwo) {
    const int blk = blockIdx.x;
    const float* s; f16_t* d; int base;
    if (blk < 4096) { s = x; d = xc; base = blk * 1024; }
    else {
        const int r = blk - 4096, which = r >> 8;
        s = (which == 0) ? wq : (which == 1) ? wk : (which == 2) ? wv : wo;
        d = (which == 0) ? dq : (which == 1) ? dk : (which == 2) ? dv : dwo;
        base = (r & 255) * 1024;
    }
    const int i = base + threadIdx.x * 4;
    const float4 v = *(const float4*)(s + i);
    f16x4 o; o[0] = (f16_t)v.x; o[1] = (f16_t)v.y;
    o[2] = (f16_t)v.z; o[3] = (f16_t)v.w;
    *(f16x4*)(d + i) = o;
}

// C = A @ B^T, f16 inputs, mfma_f32_16x16x32_f16. BK=32 (r11 config — BK=64
// measured +2us, reverted). nPerB>0: virtual B=[B0;B1;B2] (fused QKV).
// F32OUT: fp32 C (harness out buffer), else f16 C.
template<int BM, int BN, int TM, int TN, bool F32OUT>
__global__ __launch_bounds__(256) void gemm_f16(
    const f16_t* __restrict__ A, int lda,
    const f16_t* __restrict__ B0, const f16_t* __restrict__ B1,
    const f16_t* __restrict__ B2, int ldb, int nPerB,
    void* __restrict__ C, int ldc, int K)
{
    constexpr int BK = 32;
    __shared__ __align__(1024) f16_t Alds[BM * BK];
    __shared__ __align__(1024) f16_t Blds[BN * BK];

    const int tid  = threadIdx.x;
    const int lane = tid & 63;
    const int wv   = tid >> 6;
    const int wm   = wv >> 1;
    const int wn   = wv & 1;
    const int r    = lane & 15;
    const int q4   = lane >> 4;

    const int blkM = blockIdx.x * BM;
    const int colC = blockIdx.y * BN;

    const f16_t* Bp = B0;
    int nB = colC;
    if (nPerB > 0) {
        int wsel = colC / nPerB;
        nB = colC - wsel * nPerB;
        Bp = (wsel == 0) ? B0 : (wsel == 1) ? B1 : B2;
    }

    f32x4 acc[TM][TN];
    const f32x4 fzero = {0.f, 0.f, 0.f, 0.f};
    #pragma unroll
    for (int i = 0; i < TM; ++i)
        #pragma unroll
        for (int j = 0; j < TN; ++j) acc[i][j] = fzero;

    constexpr int A_LOADS = (BM * BK * 2) / (256 * 16);
    constexpr int B_LOADS = (BN * BK * 2) / (256 * 16);

    for (int kk = 0; kk < K; kk += BK) {
        __syncthreads();
        #pragma unroll
        for (int i = 0; i < A_LOADS; ++i) {
            int off  = i * 4096 + tid * 16;
            int row  = off >> 6;
            int colb = off & 63;
            const char* g = (const char*)A + ((size_t)(blkM + row) * lda + kk) * 2 + colb;
            async_copy16(g, (char*)Alds + off);
        }
        #pragma unroll
        for (int i = 0; i < B_LOADS; ++i) {
            int off  = i * 4096 + tid * 16;
            int row  = off >> 6;
            int colb = off & 63;
            const char* g = (const char*)Bp + ((size_t)(nB + row) * ldb + kk) * 2 + colb;
            async_copy16(g, (char*)Blds + off);
        }
        __syncthreads();

        f16x8 af[TM], bfr[TN];
        #pragma unroll
        for (int mt = 0; mt < TM; ++mt)
            af[mt] = *(const f16x8*)&Alds[(wm * TM * 16 + mt * 16 + r) * BK + q4 * 8];
        #pragma unroll
        for (int nt = 0; nt < TN; ++nt)
            bfr[nt] = *(const f16x8*)&Blds[(wn * TN * 16 + nt * 16 + r) * BK + q4 * 8];

        #pragma unroll
        for (int mt = 0; mt < TM; ++mt)
            #pragma unroll
            for (int nt = 0; nt < TN; ++nt)
                acc[mt][nt] = __builtin_amdgcn_mfma_f32_16x16x32_f16(
                    af[mt], bfr[nt], acc[mt][nt], 0, 0, 0);
    }

    // C/D layout: col = lane&15, row = q4*4 + reg (dtype-independent, m89).
    #pragma unroll
    for (int mt = 0; mt < TM; ++mt) {
        #pragma unroll
        for (int nt = 0; nt < TN; ++nt) {
            int rr0 = blkM + wm * TM * 16 + mt * 16 + q4 * 4;
            int cc  = colC + wn * TN * 16 + nt * 16 + r;
            #pragma unroll
            for (int i = 0; i < 4; ++i) {
                size_t o = (size_t)(rr0 + i) * ldc + cc;
                if constexpr (F32OUT) ((float*)C)[o] = acc[mt][nt][i];
                else                  ((f16_t*)C)[o] = (f16_t)acc[mt][nt][i];
            }
        }
    }
}

// Neighbor attention — r11 structure (measured best: 1 wave/(b,h,s)).
// Phase 1: lane pair (w = lane>>1, half = lane&1): 64-dim q.k via uint4
//          loads + 16 fdot2; butterfly softmax over 32 lane-pairs; no
//          max-subtraction (scores ~N(0,1); exp overflow impossible).
// Phase 2: weight packed into f16x2 (both halves), stored with V byte-offset.
// Phase 3: lane = (nh = lane>>5, d2 = lane&31): dims {2d2,2d2+1} over 16
//          neighbors; dword V load + one v_pk_fma_f16 each; 1-shuffle merge;
//          raw dword store (f16 out, zero conversions).
__global__ __launch_bounds__(256) void attn_fast(
    const f16_t* __restrict__ QKV,
    const int*   __restrict__ nidx,
    f16_t*       __restrict__ attn_out)
{
    __shared__ __align__(16) float wa_lds[4][64];  // 32 x (off_bits, w_pack)
    const int lane = threadIdx.x & 63;
    const int wv   = threadIdx.x >> 6;

    // XCD swizzle: contiguous s-range per XCD for gather L2 locality.
    const int bi  = blockIdx.x;
    const int blk = (bi & 7) * 2048 + (bi >> 3);
    const int wg  = blk * 4 + wv;                  // ((b*8+h)<<12) + s
    const int s = wg & (Sc - 1);
    const int h = (wg >> 12) & (Hc - 1);
    const int b = wg >> 15;
    const size_t row = (size_t)b * Sc + s;

    const int w    = lane >> 1;
    const int half = lane & 1;
    const int t    = nidx[s * Wc + w];

    const char* qkvB = (const char*)QKV;
    const char* Qp = qkvB + row * 3072 + h * 128 + half * 64;
    const char* Kp = qkvB + ((size_t)b * Sc + t) * 3072 + 1024 + h * 128 + half * 64;

    uint4 qv[4], kv[4];
    #pragma unroll
    for (int i = 0; i < 4; ++i) {
        qv[i] = *(const uint4*)(Qp + 16 * i);
        kv[i] = *(const uint4*)(Kp + 16 * i);
    }
    float p = 0.f;
    #pragma unroll
    for (int i = 0; i < 4; ++i) {
        p = __builtin_amdgcn_fdot2(__builtin_bit_cast(f16x2, qv[i].x),
                                   __builtin_bit_cast(f16x2, kv[i].x), p, false);
        p = __builtin_amdgcn_fdot2(__builtin_bit_cast(f16x2, qv[i].y),
                                   __builtin_bit_cast(f16x2, kv[i].y), p, false);
        p = __builtin_amdgcn_fdot2(__builtin_bit_cast(f16x2, qv[i].z),
                                   __builtin_bit_cast(f16x2, kv[i].z), p, false);
        p = __builtin_amdgcn_fdot2(__builtin_bit_cast(f16x2, qv[i].w),
                                   __builtin_bit_cast(f16x2, kv[i].w), p, false);
    }
    p += __shfl_xor(p, 1);                         // full 64-dot in both pair lanes

    // Softmax over the 32 lane-pairs (no max-sub; scores are O(1)).
    const float e = __expf(p * 0.125f);            // 1/sqrt(64)
    float sum = e;
    #pragma unroll
    for (int m = 2; m <= 32; m <<= 1) sum += __shfl_xor(sum, m);
    const float a = e / sum;

    if (half == 0) {
        const f16_t ah = (f16_t)a;
        f16x2 ap; ap[0] = ah; ap[1] = ah;
        float2 wr;
        wr.x = __int_as_float(t * 3072);
        wr.y = __builtin_bit_cast(float, ap);
        *(float2*)&wa_lds[wv][2 * w] = wr;
    }
    __syncthreads();

    // Phase 3: packed f16 accumulate.
    const int d2 = lane & 31;                      // dims 2*d2, 2*d2+1
    const int nh = lane >> 5;                      // neighbors nh*16..nh*16+15
    const float* ch = &wa_lds[wv][nh * 32];
    const char* Vp = qkvB + (size_t)b * Sc * 3072 + 2048 + h * 128 + d2 * 4;

    f16x2 acc2 = {(f16_t)0.f, (f16_t)0.f};
    #pragma unroll
    for (int j = 0; j < 8; ++j) {
        const float4 c = *(const float4*)(ch + 4 * j);
        {
            const f16x2 v2 = __builtin_bit_cast(f16x2,
                *(const unsigned*)(Vp + __float_as_int(c.x)));
            acc2 += __builtin_bit_cast(f16x2, c.y) * v2;   // v_pk_fma_f16
        }
        {
            const f16x2 v2 = __builtin_bit_cast(f16x2,
                *(const unsigned*)(Vp + __float_as_int(c.z)));
            acc2 += __builtin_bit_cast(f16x2, c.w) * v2;
        }
    }
    const int other = __shfl_xor(__builtin_bit_cast(int, acc2), 32);
    acc2 += __builtin_bit_cast(f16x2, other);
    if (nh == 0)
        *(unsigned*)((char*)attn_out + row * 1024 + h * 128 + d2 * 4) =
            __builtin_bit_cast(unsigned, acc2);
}

extern "C" void kernel_launch(void* const* d_in, const int* in_sizes, int n_in,
                              void* d_out, int out_size, void* d_ws, size_t ws_size,
                              hipStream_t stream) {
    (void)in_sizes; (void)n_in; (void)out_size; (void)ws_size;
    const int* nidx = (const int*)d_in[5];
    const int M = Bc * Sc;                        // 8192
    float* out = (float*)d_out;                   // fp32 output (round-7 finding)

    char* w = (char*)d_ws;
    f16_t* xc   = (f16_t*)(w + 256);              // 8 MB
    f16_t* Wqc  = xc  + 4194304;                  // 0.5 MB each
    f16_t* Wkc  = Wqc + 262144;
    f16_t* Wvc  = Wkc + 262144;
    f16_t* Woc  = Wvc + 262144;
    f16_t* qkv  = Woc + 262144;                   // 24 MB
    f16_t* attnS = xc;                            // reuse x-buffer after GEMM1

    convert_all<<<5120, 256, 0, stream>>>(
        (const float*)d_in[0], (const float*)d_in[1], (const float*)d_in[2],
        (const float*)d_in[3], (const float*)d_in[4],
        xc, Wqc, Wkc, Wvc, Woc);

    // Fused QKV projection: M=8192, N=1536, K=512 (f16 out).
    gemm_f16<128, 128, 4, 4, false><<<dim3(M / 128, 1536 / 128), 256, 0, stream>>>(
        xc, Dc, Wqc, Wkc, Wvc, Dc, 512, qkv, 1536, Dc);

    // Neighbor attention: one wave per (b,h,s).
    attn_fast<<<(Bc * Hc * Sc) / 4, 256, 0, stream>>>(qkv, nidx, attnS);

    // Output projection: M=8192, N=512, K=512 -> fp32 d_out.
    gemm_f16<128, 64, 4, 2, true><<<dim3(M / 128, 512 / 64), 256, 0, stream>>>(
        attnS, 512, Woc, Woc, Woc, 512, 0, out, Dc, Dc);
}